// Round 1
// 209.917 us; speedup vs baseline: 1.0269x; 1.0269x over previous
//
#include <hip/hip_runtime.h>

// 1 - alpha = (1 + exp(density+shift))^(-0.5) = rsqrt(u), u = 1 + exp(x).
// alpha * (1/(1-alpha)) = u*a - 1, so w = T_incl * (u*a - 1).

__device__ __forceinline__ float fast_sigmoid(float x) {
    return __builtin_amdgcn_rcpf(1.0f + __expf(-x));
}

// ---- DPP wave64 scans ------------------------------------------------------
#define DPP_ADD(x, ctrl, rmask)                                               \
    do {                                                                      \
        int _s = __builtin_amdgcn_update_dpp(0, __float_as_int(x), (ctrl),    \
                                             (rmask), 0xf, true);             \
        (x) += __int_as_float(_s);                                            \
    } while (0)

#define DPP_MUL(x, ctrl, rmask)                                               \
    do {                                                                      \
        int _s = __builtin_amdgcn_update_dpp(0x3f800000, __float_as_int(x),   \
                                             (ctrl), (rmask), 0xf, false);    \
        (x) *= __int_as_float(_s);                                            \
    } while (0)

__device__ __forceinline__ float wave_scan_add(float x) {
    DPP_ADD(x, 0x111, 0xf);  // row_shr:1
    DPP_ADD(x, 0x112, 0xf);  // row_shr:2
    DPP_ADD(x, 0x114, 0xf);  // row_shr:4
    DPP_ADD(x, 0x118, 0xf);  // row_shr:8
    DPP_ADD(x, 0x142, 0xa);  // row_bcast:15 -> rows 1,3
    DPP_ADD(x, 0x143, 0xc);  // row_bcast:31 -> rows 2,3
    return x;
}

__device__ __forceinline__ float wave_scan_mul(float x) {
    DPP_MUL(x, 0x111, 0xf);
    DPP_MUL(x, 0x112, 0xf);
    DPP_MUL(x, 0x114, 0xf);
    DPP_MUL(x, 0x118, 0xf);
    DPP_MUL(x, 0x142, 0xa);
    DPP_MUL(x, 0x143, 0xc);
    return x;
}

__device__ __forceinline__ float bcast_lane63(float x) {
    return __int_as_float(__builtin_amdgcn_readlane(__float_as_int(x), 63));
}

// ---- Pass 1: segment starts (int4-vectorized boundary detection) -----------
__global__ __launch_bounds__(256) void seg_starts4_kernel(
    const int4* __restrict__ ray4, int M4, int M, int N,
    const int* __restrict__ ray_id, int* __restrict__ starts)
{
    const int i = blockIdx.x * blockDim.x + threadIdx.x;
    if (i >= M4) return;
    const int4 v = ray4[i];
    const int prev = (i == 0) ? -1 : ray_id[4 * i - 1];
    const int base = 4 * i;
    for (int r = prev + 1; r <= v.x; ++r) starts[r] = base;
    for (int r = v.x + 1;  r <= v.y; ++r) starts[r] = base + 1;
    for (int r = v.y + 1;  r <= v.z; ++r) starts[r] = base + 2;
    for (int r = v.z + 1;  r <= v.w; ++r) starts[r] = base + 3;
    if (i == M4 - 1) {
        int last = v.w;
        for (int j = 4 * M4; j < M; ++j) {      // scalar tail (M%4)
            const int cur = ray_id[j];
            for (int r = last + 1; r <= cur; ++r) starts[r] = j;
            last = cur;
        }
        for (int r = last + 1; r <= N; ++r) starts[r] = M;
    }
}

// ---- Pass 2: RPW rays per wave ---------------------------------------------
// Counts per ray ~ Poisson(64): essentially every ray has 1 or 2 chunks.
// Strategy: prefetch BOTH chunks of all RPW rays up front (32 loads in
// flight), compute chunk-0 of all rays, then chunk-1 of all rays BRANCHLESS
// (valid-masked; tot==1 when absent) so the whole hot path is straight-line
// code and the compiler cannot sink the prefetch into conditional blocks.
// __launch_bounds__(256,4) relaxes the VGPR budget so the scheduler keeps
// the loads hoisted (the previous build allocated only 20 VGPRs -> loads
// were serialized into each ray's critical path).
#define RPW 4

__global__ __launch_bounds__(256, 4) void favor_render_kernel(
    const float* __restrict__ density,
    const float* __restrict__ rgb_feat,   // [M,3]
    const float* __restrict__ shift,      // [1]
    const int*   __restrict__ starts,     // [N+1]
    int M, int N,
    float* __restrict__ weights,          // [M]
    float* __restrict__ alphainv_last,    // [N]
    float* __restrict__ out3)             // [N,3]
{
    const int wave = (blockIdx.x * blockDim.x + threadIdx.x) >> 6;
    const int t    = threadIdx.x & 63;
    const int r0   = wave * RPW;
    if (r0 >= N) return;

    // Bounds for all RPW rays: one coalesced load, broadcast to SGPRs.
    const int bv = starts[min(r0 + t, N)];
    int s[RPW + 1];
    #pragma unroll
    for (int k = 0; k <= RPW; ++k)
        s[k] = __builtin_amdgcn_readlane(bv, k);

    const float sh = shift[0];

    // ---- Phase A: issue ALL loads (chunk0 + chunk1, RPW rays) up front ----
    float d0[RPW], r0v[RPW], g0v[RPW], b0v[RPW];
    float d1[RPW], r1v[RPW], g1v[RPW], b1v[RPW];
    #pragma unroll
    for (int j = 0; j < RPW; ++j) {
        const int st = s[j], en = s[j + 1];
        const int c0 = max(min(st + t,      en - 1), 0);
        const int c1 = max(min(st + 64 + t, en - 1), 0);  // short ray -> 1-line bcast
        d0[j]  = density[c0];
        r0v[j] = rgb_feat[3 * c0 + 0];
        g0v[j] = rgb_feat[3 * c0 + 1];
        b0v[j] = rgb_feat[3 * c0 + 2];
        d1[j]  = density[c1];
        r1v[j] = rgb_feat[3 * c1 + 0];
        g1v[j] = rgb_feat[3 * c1 + 1];
        b1v[j] = rgb_feat[3 * c1 + 2];
    }

    float carryT[RPW], accR[RPW], accG[RPW], accB[RPW];

    // ---- Phase B: chunk-0 of all rays (4 independent chains, full ILP) ----
    #pragma unroll
    for (int j = 0; j < RPW; ++j) {
        const int st = s[j], en = s[j + 1];
        const bool valid = (st + t) < en;
        const float u = 1.0f + __expf(d0[j] + sh);
        const float a = __builtin_amdgcn_rsqf(u);      // 1 - alpha
        const float m = valid ? a : 1.0f;
        const float S = wave_scan_mul(m);              // inclusive product
        carryT[j] = bcast_lane63(S);
        const float w = S * (u * a - 1.0f);            // T_excl * alpha
        accR[j] = valid ? w * fast_sigmoid(r0v[j]) : 0.0f;
        accG[j] = valid ? w * fast_sigmoid(g0v[j]) : 0.0f;
        accB[j] = valid ? w * fast_sigmoid(b0v[j]) : 0.0f;
        if (valid) weights[st + t] = w;
    }

    // ---- Phase C: chunk-1 of all rays, BRANCHLESS ----
    // If the ray has no chunk-1, all lanes are invalid -> m=1, S=1, tot=1:
    // carryT and accumulators are unchanged, nothing stored.
    #pragma unroll
    for (int j = 0; j < RPW; ++j) {
        const int st = s[j], en = s[j + 1];
        const int i = st + 64 + t;
        const bool valid = i < en;
        const float u = 1.0f + __expf(d1[j] + sh);
        const float a = __builtin_amdgcn_rsqf(u);
        const float m = valid ? a : 1.0f;
        const float S = wave_scan_mul(m);
        const float tot = bcast_lane63(S);
        const float w = carryT[j] * S * (u * a - 1.0f);
        accR[j] += valid ? w * fast_sigmoid(r1v[j]) : 0.0f;
        accG[j] += valid ? w * fast_sigmoid(g1v[j]) : 0.0f;
        accB[j] += valid ? w * fast_sigmoid(b1v[j]) : 0.0f;
        if (valid) weights[i] = w;
        carryT[j] *= tot;
    }

    // ---- Phase D: chunks >= 2 (Poisson(64) tail: essentially never) ----
    #pragma unroll
    for (int j = 0; j < RPW; ++j) {
        const int st = s[j], en = s[j + 1];
        for (int base = st + 128; base < en; base += 64) {
            const int i = base + t;
            const bool valid = i < en;
            const int c = min(i, en - 1);
            const float d = density[c];
            const float r = rgb_feat[3 * c + 0];
            const float g = rgb_feat[3 * c + 1];
            const float b = rgb_feat[3 * c + 2];
            const float u = 1.0f + __expf(d + sh);
            const float a = __builtin_amdgcn_rsqf(u);
            const float m = valid ? a : 1.0f;
            const float S = wave_scan_mul(m);
            const float tot = bcast_lane63(S);
            const float w = carryT[j] * S * (u * a - 1.0f);
            if (valid) {
                weights[i] = w;
                accR[j] += w * fast_sigmoid(r);
                accG[j] += w * fast_sigmoid(g);
                accB[j] += w * fast_sigmoid(b);
            }
            carryT[j] *= tot;
        }
    }

    // ---- Phase E: epilogue — 12 independent DPP reduce chains, batched ----
    float tR[RPW], tG[RPW], tB[RPW];
    #pragma unroll
    for (int j = 0; j < RPW; ++j) {
        tR[j] = wave_scan_add(accR[j]);
        tG[j] = wave_scan_add(accG[j]);
        tB[j] = wave_scan_add(accB[j]);
    }
    #pragma unroll
    for (int j = 0; j < RPW; ++j) {
        const float sR = bcast_lane63(tR[j]);
        const float sG = bcast_lane63(tG[j]);
        const float sB = bcast_lane63(tB[j]);
        const int ray = r0 + j;
        if (t == 0 && ray < N) {
            alphainv_last[ray] = carryT[j];
            out3[3 * ray + 0] = sR + carryT[j];
            out3[3 * ray + 1] = sG + carryT[j];
            out3[3 * ray + 2] = sB + carryT[j];
        }
    }
}

extern "C" void kernel_launch(void* const* d_in, const int* in_sizes, int n_in,
                              void* d_out, int out_size, void* d_ws, size_t ws_size,
                              hipStream_t stream) {
    const float* density  = (const float*)d_in[0];
    const float* rgb_feat = (const float*)d_in[1];
    const float* shift    = (const float*)d_in[2];
    const int*   ray_id   = (const int*)d_in[3];

    const int M = in_sizes[0];
    const int N = (out_size - M) / 4;   // out_size = M + N + 3N

    float* weights       = (float*)d_out;
    float* alphainv_last = weights + M;
    float* out3          = alphainv_last + N;

    const int block = 256;
    int* starts = (int*)d_ws;

    const int M4 = M >> 2;
    const int grid_starts = (M4 + block - 1) / block;
    seg_starts4_kernel<<<grid_starts, block, 0, stream>>>(
        (const int4*)ray_id, M4, M, N, ray_id, starts);

    const int n_waves = (N + RPW - 1) / RPW;
    const int grid_render = (n_waves * 64 + block - 1) / block;
    favor_render_kernel<<<grid_render, block, 0, stream>>>(
        density, rgb_feat, shift, starts, M, N,
        weights, alphainv_last, out3);
}

// Round 2
// 208.500 us; speedup vs baseline: 1.0339x; 1.0068x over previous
//
#include <hip/hip_runtime.h>

// 1 - alpha = (1 + exp(density+shift))^(-0.5) = rsqrt(u), u = 1 + exp(x).
// alpha * (1/(1-alpha)) = u*a - 1, so w = T_incl * (u*a - 1).

__device__ __forceinline__ float fast_sigmoid(float x) {
    return __builtin_amdgcn_rcpf(1.0f + __expf(-x));
}

// ---- DPP wave64 scans ------------------------------------------------------
#define DPP_ADD(x, ctrl, rmask)                                               \
    do {                                                                      \
        int _s = __builtin_amdgcn_update_dpp(0, __float_as_int(x), (ctrl),    \
                                             (rmask), 0xf, true);             \
        (x) += __int_as_float(_s);                                            \
    } while (0)

#define DPP_MUL(x, ctrl, rmask)                                               \
    do {                                                                      \
        int _s = __builtin_amdgcn_update_dpp(0x3f800000, __float_as_int(x),   \
                                             (ctrl), (rmask), 0xf, false);    \
        (x) *= __int_as_float(_s);                                            \
    } while (0)

__device__ __forceinline__ float wave_scan_add(float x) {
    DPP_ADD(x, 0x111, 0xf);  // row_shr:1
    DPP_ADD(x, 0x112, 0xf);  // row_shr:2
    DPP_ADD(x, 0x114, 0xf);  // row_shr:4
    DPP_ADD(x, 0x118, 0xf);  // row_shr:8
    DPP_ADD(x, 0x142, 0xa);  // row_bcast:15 -> rows 1,3
    DPP_ADD(x, 0x143, 0xc);  // row_bcast:31 -> rows 2,3
    return x;
}

__device__ __forceinline__ float wave_scan_mul(float x) {
    DPP_MUL(x, 0x111, 0xf);
    DPP_MUL(x, 0x112, 0xf);
    DPP_MUL(x, 0x114, 0xf);
    DPP_MUL(x, 0x118, 0xf);
    DPP_MUL(x, 0x142, 0xa);
    DPP_MUL(x, 0x143, 0xc);
    return x;
}

__device__ __forceinline__ float bcast_lane63(float x) {
    return __int_as_float(__builtin_amdgcn_readlane(__float_as_int(x), 63));
}

// ---- Pass 1: segment starts (int4-vectorized boundary detection) -----------
__global__ __launch_bounds__(256) void seg_starts4_kernel(
    const int4* __restrict__ ray4, int M4, int M, int N,
    const int* __restrict__ ray_id, int* __restrict__ starts)
{
    const int i = blockIdx.x * blockDim.x + threadIdx.x;
    if (i >= M4) return;
    const int4 v = ray4[i];
    const int prev = (i == 0) ? -1 : ray_id[4 * i - 1];
    const int base = 4 * i;
    for (int r = prev + 1; r <= v.x; ++r) starts[r] = base;
    for (int r = v.x + 1;  r <= v.y; ++r) starts[r] = base + 1;
    for (int r = v.y + 1;  r <= v.z; ++r) starts[r] = base + 2;
    for (int r = v.z + 1;  r <= v.w; ++r) starts[r] = base + 3;
    if (i == M4 - 1) {
        int last = v.w;
        for (int j = 4 * M4; j < M; ++j) {      // scalar tail (M%4)
            const int cur = ray_id[j];
            for (int r = last + 1; r <= cur; ++r) starts[r] = j;
            last = cur;
        }
        for (int r = last + 1; r <= N; ++r) starts[r] = M;
    }
}

// ---- Pass 2: RPW rays per wave ---------------------------------------------
// Counts per ray ~ Poisson(64): essentially every ray has 1 or 2 chunks.
// - Prefetch chunk0 of all rays, then chunk1 of all rays (ordered so counted
//   vmcnt waits release chunk-0 compute after only the first 16 loads).
// - sched_barrier(0) after the load phase: compile-time fence, scheduler
//   cannot sink the prefetch into the compute (VGPR=32 last build proved it
//   was re-serializing half the loads).
// - chunk-1 compute is skipped per-ray via a SCALAR branch (s[] are uniform
//   readlane results): ~50% of rays are short -> saves ~25% of all VALU work.
//   Skipped chunk-1 is numerically the identity (S=1, tot=1, no stores).
#define RPW 4

__global__ __launch_bounds__(256, 4) void favor_render_kernel(
    const float* __restrict__ density,
    const float* __restrict__ rgb_feat,   // [M,3]
    const float* __restrict__ shift,      // [1]
    const int*   __restrict__ starts,     // [N+1]
    int M, int N,
    float* __restrict__ weights,          // [M]
    float* __restrict__ alphainv_last,    // [N]
    float* __restrict__ out3)             // [N,3]
{
    const int wave = (blockIdx.x * blockDim.x + threadIdx.x) >> 6;
    const int t    = threadIdx.x & 63;
    const int r0   = wave * RPW;
    if (r0 >= N) return;

    // Bounds for all RPW rays: one coalesced load, broadcast to SGPRs.
    const int bv = starts[min(r0 + t, N)];
    int s[RPW + 1];
    #pragma unroll
    for (int k = 0; k <= RPW; ++k)
        s[k] = __builtin_amdgcn_readlane(bv, k);

    const float sh = shift[0];

    // ---- Phase A: issue ALL loads up front (chunk0 first, then chunk1) ----
    float d0[RPW], r0v[RPW], g0v[RPW], b0v[RPW];
    float d1[RPW], r1v[RPW], g1v[RPW], b1v[RPW];
    #pragma unroll
    for (int j = 0; j < RPW; ++j) {
        const int st = s[j], en = s[j + 1];
        const int c0 = max(min(st + t, en - 1), 0);
        d0[j]  = density[c0];
        r0v[j] = rgb_feat[3 * c0 + 0];
        g0v[j] = rgb_feat[3 * c0 + 1];
        b0v[j] = rgb_feat[3 * c0 + 2];
    }
    #pragma unroll
    for (int j = 0; j < RPW; ++j) {
        const int st = s[j], en = s[j + 1];
        const int c1 = max(min(st + 64 + t, en - 1), 0);  // short ray -> bcast
        d1[j]  = density[c1];
        r1v[j] = rgb_feat[3 * c1 + 0];
        g1v[j] = rgb_feat[3 * c1 + 1];
        b1v[j] = rgb_feat[3 * c1 + 2];
    }
    // Compile-time fence: nothing may move across — all 32 loads are issued
    // before any compute, regardless of register-pressure heuristics.
    __builtin_amdgcn_sched_barrier(0);

    float carryT[RPW], accR[RPW], accG[RPW], accB[RPW];

    // ---- Phase B: chunk-0 of all rays (4 independent chains, full ILP) ----
    #pragma unroll
    for (int j = 0; j < RPW; ++j) {
        const int st = s[j], en = s[j + 1];
        const bool valid = (st + t) < en;
        const float u = 1.0f + __expf(d0[j] + sh);
        const float a = __builtin_amdgcn_rsqf(u);      // 1 - alpha
        const float m = valid ? a : 1.0f;
        const float S = wave_scan_mul(m);              // inclusive product
        carryT[j] = bcast_lane63(S);
        const float w = S * (u * a - 1.0f);            // T_excl * alpha
        accR[j] = valid ? w * fast_sigmoid(r0v[j]) : 0.0f;
        accG[j] = valid ? w * fast_sigmoid(g0v[j]) : 0.0f;
        accB[j] = valid ? w * fast_sigmoid(b0v[j]) : 0.0f;
        if (valid) weights[st + t] = w;
    }

    // ---- Phase C: chunk-1, skipped per-ray by a SCALAR (uniform) branch ----
    #pragma unroll
    for (int j = 0; j < RPW; ++j) {
        const int st = s[j], en = s[j + 1];
        if (en - st > 64) {                 // uniform: s_cbranch, no divergence
            const int i = st + 64 + t;
            const bool valid = i < en;
            const float u = 1.0f + __expf(d1[j] + sh);
            const float a = __builtin_amdgcn_rsqf(u);
            const float m = valid ? a : 1.0f;
            const float S = wave_scan_mul(m);
            const float tot = bcast_lane63(S);
            const float w = carryT[j] * S * (u * a - 1.0f);
            accR[j] += valid ? w * fast_sigmoid(r1v[j]) : 0.0f;
            accG[j] += valid ? w * fast_sigmoid(g1v[j]) : 0.0f;
            accB[j] += valid ? w * fast_sigmoid(b1v[j]) : 0.0f;
            if (valid) weights[i] = w;
            carryT[j] *= tot;

            // ---- chunks >= 2 (Poisson(64) tail: rare) ----
            for (int base = st + 128; base < en; base += 64) {
                const int ii = base + t;
                const bool v2 = ii < en;
                const int c = min(ii, en - 1);
                const float dd = density[c];
                const float rr = rgb_feat[3 * c + 0];
                const float gg = rgb_feat[3 * c + 1];
                const float bb = rgb_feat[3 * c + 2];
                const float u2 = 1.0f + __expf(dd + sh);
                const float a2 = __builtin_amdgcn_rsqf(u2);
                const float m2 = v2 ? a2 : 1.0f;
                const float S2 = wave_scan_mul(m2);
                const float tot2 = bcast_lane63(S2);
                const float w2 = carryT[j] * S2 * (u2 * a2 - 1.0f);
                if (v2) {
                    weights[ii] = w2;
                    accR[j] += w2 * fast_sigmoid(rr);
                    accG[j] += w2 * fast_sigmoid(gg);
                    accB[j] += w2 * fast_sigmoid(bb);
                }
                carryT[j] *= tot2;
            }
        }
    }

    // ---- Phase E: epilogue — 12 independent DPP reduce chains, batched ----
    float tR[RPW], tG[RPW], tB[RPW];
    #pragma unroll
    for (int j = 0; j < RPW; ++j) {
        tR[j] = wave_scan_add(accR[j]);
        tG[j] = wave_scan_add(accG[j]);
        tB[j] = wave_scan_add(accB[j]);
    }
    #pragma unroll
    for (int j = 0; j < RPW; ++j) {
        const float sR = bcast_lane63(tR[j]);
        const float sG = bcast_lane63(tG[j]);
        const float sB = bcast_lane63(tB[j]);
        const int ray = r0 + j;
        if (t == 0 && ray < N) {
            alphainv_last[ray] = carryT[j];
            out3[3 * ray + 0] = sR + carryT[j];
            out3[3 * ray + 1] = sG + carryT[j];
            out3[3 * ray + 2] = sB + carryT[j];
        }
    }
}

extern "C" void kernel_launch(void* const* d_in, const int* in_sizes, int n_in,
                              void* d_out, int out_size, void* d_ws, size_t ws_size,
                              hipStream_t stream) {
    const float* density  = (const float*)d_in[0];
    const float* rgb_feat = (const float*)d_in[1];
    const float* shift    = (const float*)d_in[2];
    const int*   ray_id   = (const int*)d_in[3];

    const int M = in_sizes[0];
    const int N = (out_size - M) / 4;   // out_size = M + N + 3N

    float* weights       = (float*)d_out;
    float* alphainv_last = weights + M;
    float* out3          = alphainv_last + N;

    const int block = 256;
    int* starts = (int*)d_ws;

    const int M4 = M >> 2;
    const int grid_starts = (M4 + block - 1) / block;
    seg_starts4_kernel<<<grid_starts, block, 0, stream>>>(
        (const int4*)ray_id, M4, M, N, ray_id, starts);

    const int n_waves = (N + RPW - 1) / RPW;
    const int grid_render = (n_waves * 64 + block - 1) / block;
    favor_render_kernel<<<grid_render, block, 0, stream>>>(
        density, rgb_feat, shift, starts, M, N,
        weights, alphainv_last, out3);
}